// Round 8
// baseline (1423.160 us; speedup 1.0000x reference)
//
#include <hip/hip_runtime.h>
#include <hip/hip_bf16.h>

typedef __attribute__((ext_vector_type(8))) short bf16x8;
typedef __attribute__((ext_vector_type(4))) float f32x4;
typedef __attribute__((ext_vector_type(4))) int   i32x4;
typedef __attribute__((ext_vector_type(4))) unsigned short u16x4;
typedef unsigned short u16;

#define G_ 20000
#define B_ 512
#define SLAB_U16 16384   // one K=32 slab: [4 chunks][512 rows][8 u16] = 32 KB

__device__ __forceinline__ u16 f2bf(float x) {
  __hip_bfloat16 h = __float2bfloat16(x);   // RTN
  return __builtin_bit_cast(u16, h);
}

__device__ __forceinline__ void glds16(const void* g, void* l) {
  __builtin_amdgcn_global_load_lds(
      (const __attribute__((address_space(1))) void*)g,
      (__attribute__((address_space(3))) void*)l, 16, 0, 0);
}

// within-slab u16 index for logical (row b, col kk in [0,32)):
// layout [chunk=kk>>3][row][kk&7]
__device__ __forceinline__ int aidx(int b, int kk) {
  return ((kk >> 3) & 3) * 4096 + b * 8 + (kk & 7);
}

// ---------------------------------------------------------------------------
// K1: per-gene micro-MLP -> X slabs (chunked layout), cols 0..19999.
// blockIdx.x==79 handles clinical cols 20000..20095 (38 real + zero pad).
// ---------------------------------------------------------------------------
__global__ void k_gene(const float* __restrict__ expr,
                       const float* __restrict__ bw1, const float* __restrict__ bb1,
                       const float* __restrict__ bw2, const float* __restrict__ bb2,
                       const float* __restrict__ gw,  const float* __restrict__ gb,
                       const int* __restrict__ cc, const float* __restrict__ cnc,
                       const float* __restrict__ race, const float* __restrict__ eth,
                       const float* __restrict__ inter, const float* __restrict__ prot,
                       const float* __restrict__ mw, const float* __restrict__ mb,
                       u16* __restrict__ Xt) {
  int b0 = blockIdx.y * 32;

  if (blockIdx.x == 79) {
    int b = b0 + (threadIdx.x >> 3);
    int j0 = (threadIdx.x & 7) * 12;
    int c0 = cc[b * 3], c1 = cc[b * 3 + 1], c2 = cc[b * 3 + 2];
    float nc[10];
    #pragma unroll
    for (int v = 0; v < 10; ++v)
      nc[v] = fmaxf(cnc[b * 20 + v] * mw[v * 2] + cnc[b * 20 + 10 + v] * mw[v * 2 + 1] + mb[v], 0.f);
    #pragma unroll
    for (int jj = 0; jj < 12; ++jj) {
      int j = j0 + jj;
      float v;
      if (j < 8)       v = race[c0 * 8 + j];
      else if (j < 12) v = eth[c1 * 4 + (j - 8)];
      else if (j < 20) v = inter[(c0 * 4 + c1) * 8 + (j - 12)];
      else if (j < 28) v = prot[c2 * 8 + (j - 20)];
      else if (j < 38) v = nc[j - 28];
      else             v = 0.f;
      int k = 20000 + j;
      Xt[(size_t)(k >> 5) * SLAB_U16 + aidx(b, k & 31)] = f2bf(v);
    }
    return;
  }

  int g = blockIdx.x * 256 + threadIdx.x;
  if (g >= G_) return;

  f32x4 w1a = ((const f32x4*)bw1)[g];
  f32x4 w1b = ((const f32x4*)bw1)[G_ + g];
  f32x4 b1a = ((const f32x4*)bb1)[g];
  f32x4 b1b = ((const f32x4*)bb1)[G_ + g];
  f32x4 w2a = ((const f32x4*)bw2)[g];
  f32x4 w2b = ((const f32x4*)bw2)[G_ + g];
  float bb2a = bb2[g], bb2b = bb2[G_ + g];
  float gw0 = gw[g * 2], gw1 = gw[g * 2 + 1];
  float gbg = gb[g];

  u16* slab = Xt + (size_t)(g >> 5) * SLAB_U16;
  int co = ((g >> 3) & 3) * 4096 + (g & 7);

  #pragma unroll 4
  for (int b = b0; b < b0 + 32; ++b) {
    float x0 = expr[(size_t)(b * 2) * G_ + g];
    float x1 = expr[(size_t)(b * 2 + 1) * G_ + g];
    float h0 = fmaxf(x0 * w1a.x + b1a.x, 0.f);
    float h1 = fmaxf(x0 * w1a.y + b1a.y, 0.f);
    float h2 = fmaxf(x0 * w1a.z + b1a.z, 0.f);
    float h3 = fmaxf(x0 * w1a.w + b1a.w, 0.f);
    float s0 = fmaxf(h0 * w2a.x + h1 * w2a.y + h2 * w2a.z + h3 * w2a.w + bb2a, 0.f);
    float g0 = fmaxf(x1 * w1b.x + b1b.x, 0.f);
    float g1 = fmaxf(x1 * w1b.y + b1b.y, 0.f);
    float g2 = fmaxf(x1 * w1b.z + b1b.z, 0.f);
    float g3 = fmaxf(x1 * w1b.w + b1b.w, 0.f);
    float s1 = fmaxf(g0 * w2b.x + g1 * w2b.y + g2 * w2b.z + g3 * w2b.w + bb2b, 0.f);
    float e = fmaxf(s0 * gw0 + s1 * gw1 + gbg, 0.f);
    slab[co + b * 8] = f2bf(e);
  }
}

// ---------------------------------------------------------------------------
// GEMM: BM=512 BN=256 BK=32, 1024 threads (16 waves, 4x4, wave-tile 128x64).
// 96 KB LDS (A dbuf 2x32K, B dbuf 2x16K). A via global_load_lds; W reg->bf16.
// One barrier + one vmcnt(0) per iter; loads issued at top, waited after
// COMPUTE (slack = full compute phase). A-refetch traffic = (N/256) * 20 MB.
// ---------------------------------------------------------------------------
__global__ __launch_bounds__(1024) void k_gemm(
    const u16* __restrict__ Xt, const float* __restrict__ W,
    float* __restrict__ part, int nSlabs, int Kvalid, int Nvalid, int Npad) {
  __shared__ __align__(16) u16 As[2][SLAB_U16];  // 2 x 32 KB, [4][512][8]
  __shared__ __align__(16) u16 Bs[2][8192];      // 2 x 16 KB, [4][256][8]

  const int tid = threadIdx.x;
  const int nt = blockIdx.x, split = blockIdx.y, S = gridDim.y;
  const int n0 = nt * 256;
  const int s0 = (int)(((long)split * nSlabs) / S);
  const int s1 = (int)(((long)(split + 1) * nSlabs) / S);
  const int sLast = s1 - 1;

  const int lane = tid & 63, wv = tid >> 6;     // 16 waves
  const int wr = wv >> 2, wc = wv & 3;          // 4x4 wave grid
  const int l15 = lane & 15, l4 = lane >> 4;
  const int bn = tid & 255, kq = tid >> 8;      // W staging: col, k-octant
  const int nW = n0 + bn;
  const bool nok = nW < Nvalid;

  f32x4 acc[8][4];
  #pragma unroll
  for (int i = 0; i < 8; ++i)
    #pragma unroll
    for (int j = 0; j < 4; ++j) acc[i][j] = f32x4{0.f, 0.f, 0.f, 0.f};

  float wreg[8];

  auto GLDS = [&](int s, int buf) {
    const char* sb = (const char*)(Xt + (size_t)s * SLAB_U16);
    char* lb = (char*)&As[buf][0];
    #pragma unroll
    for (int j = 0; j < 2; ++j) {
      int q = wv * 2 + j;                       // 1-KB unit, wave-uniform dest
      glds16(sb + q * 1024 + lane * 16, lb + q * 1024);
    }
  };
  auto WLOAD = [&](int s) {
    int kb = s * 32 + kq * 8;
    #pragma unroll
    for (int j = 0; j < 8; ++j) {
      int k = kb + j;
      wreg[j] = (nok && k < Kvalid) ? W[(size_t)k * Nvalid + nW] : 0.f;
    }
  };
  auto BSTORE = [&](int buf) {
    i32x4 pk;
    #pragma unroll
    for (int q = 0; q < 4; ++q)
      pk[q] = (int)(unsigned)f2bf(wreg[q * 2]) |
              ((int)(unsigned)f2bf(wreg[q * 2 + 1]) << 16);
    *(i32x4*)&Bs[buf][kq * 2048 + bn * 8] = pk;   // 8 u16 contiguous
  };
  auto COMPUTE = [&](int buf) {
    bf16x8 bfr[4];
    #pragma unroll
    for (int nf = 0; nf < 4; ++nf)
      bfr[nf] = *(const bf16x8*)&Bs[buf][l4 * 2048 + (wc * 64 + nf * 16 + l15) * 8];
    #pragma unroll
    for (int mf = 0; mf < 8; ++mf) {
      bf16x8 af = *(const bf16x8*)&As[buf][l4 * 4096 + (wr * 128 + mf * 16 + l15) * 8];
      #pragma unroll
      for (int nf = 0; nf < 4; ++nf)
        acc[mf][nf] = __builtin_amdgcn_mfma_f32_16x16x32_bf16(af, bfr[nf], acc[mf][nf], 0, 0, 0);
    }
  };

  // prologue: stage slab s0 into buffer 0
  GLDS(s0, 0); WLOAD(s0);
  asm volatile("s_waitcnt vmcnt(0)" ::: "memory");
  BSTORE(0);
  asm volatile("s_waitcnt lgkmcnt(0)" ::: "memory");
  __builtin_amdgcn_s_barrier();

  int c = 0;
  for (int s = s0; s < s1; ++s) {
    if (s < sLast) { GLDS(s + 1, c ^ 1); WLOAD(s + 1); }  // issue early
    COMPUTE(c);                                           // ~2000+ cyc of slack
    if (s < sLast) {
      asm volatile("s_waitcnt vmcnt(0)" ::: "memory");    // s+1 loads landed
      BSTORE(c ^ 1);
      asm volatile("s_waitcnt lgkmcnt(0)" ::: "memory");
      __builtin_amdgcn_s_barrier();                       // buf c^1 ready for all
    }
    c ^= 1;
  }

  float* outp = part + (size_t)split * B_ * Npad;
  #pragma unroll
  for (int mf = 0; mf < 8; ++mf)
    #pragma unroll
    for (int nf = 0; nf < 4; ++nf) {
      int col = n0 + wc * 64 + nf * 16 + l15;
      int rb = wr * 128 + mf * 16 + l4 * 4;
      #pragma unroll
      for (int r = 0; r < 4; ++r)
        outp[(size_t)(rb + r) * Npad + col] = acc[mf][nf][r];
    }
}

// ---------------------------------------------------------------------------
// Reduce split-K partials + bias + ReLU -> bf16 chunked slab activations
// ---------------------------------------------------------------------------
__global__ void k_reduce(const float* __restrict__ part, const float* __restrict__ bias,
                         u16* __restrict__ Ht, int S, int Npad, int Nout, int Nvalid) {
  int idx = blockIdx.x * 256 + threadIdx.x;
  int perRow = Nout >> 2;
  if (idx >= B_ * perRow) return;
  int b = idx / perRow;
  int n = (idx - b * perRow) * 4;
  float v[4] = {0.f, 0.f, 0.f, 0.f};
  for (int s = 0; s < S; ++s) {
    const f32x4 p = *(const f32x4*)&part[(size_t)s * B_ * Npad + (size_t)b * Npad + n];
    #pragma unroll
    for (int r = 0; r < 4; ++r) v[r] += p[r];
  }
  u16x4 o;
  #pragma unroll
  for (int r = 0; r < 4; ++r) {
    float bi = (n + r < Nvalid) ? bias[n + r] : 0.f;
    o[r] = f2bf(fmaxf(v[r] + bi, 0.f));
  }
  *(u16x4*)&Ht[(size_t)(n >> 5) * SLAB_U16 + aidx(b, n & 31)] = o;
}

// ---------------------------------------------------------------------------
// Fused tail: reduce L2 partials (+bias+relu) -> L3 (313->78) -> L4 (78->2)
// ---------------------------------------------------------------------------
__global__ void k_tail(const float* __restrict__ part2, const float* __restrict__ b2,
                       const float* __restrict__ W3, const float* __restrict__ b3,
                       const float* __restrict__ W4, const float* __restrict__ b4,
                       int S2, int Npad2, float* __restrict__ out) {
  __shared__ float h3[320];
  __shared__ float h4[80];
  int b = blockIdx.x, tid = threadIdx.x;  // 128 threads
  for (int n = tid; n < 320; n += 128) {
    float v = 0.f;
    for (int s = 0; s < S2; ++s)
      v += part2[(size_t)s * B_ * Npad2 + (size_t)b * Npad2 + n];
    float bi = (n < 313) ? b2[n] : 0.f;
    h3[n] = fmaxf(v + bi, 0.f);
  }
  __syncthreads();
  if (tid < 78) {
    float a = b3[tid];
    #pragma unroll 4
    for (int k = 0; k < 313; ++k) a += h3[k] * W3[k * 78 + tid];
    h4[tid] = fmaxf(a, 0.f);
  }
  __syncthreads();
  if (tid < 2) {
    float a = b4[tid];
    for (int k = 0; k < 78; ++k) a += h4[k] * W4[k * 2 + tid];
    out[b * 2 + tid] = a;
  }
}

// ---------------------------------------------------------------------------
extern "C" void kernel_launch(void* const* d_in, const int* in_sizes, int n_in,
                              void* d_out, int out_size, void* d_ws, size_t ws_size,
                              hipStream_t stream) {
  const float* expr = (const float*)d_in[0];
  const int*   cc   = (const int*)d_in[1];
  const float* cnc  = (const float*)d_in[2];
  const float* bw1  = (const float*)d_in[3];
  const float* bb1  = (const float*)d_in[4];
  const float* bw2  = (const float*)d_in[5];
  const float* bb2  = (const float*)d_in[6];
  const float* gw   = (const float*)d_in[7];
  const float* gb   = (const float*)d_in[8];
  const float* race = (const float*)d_in[9];
  const float* eth  = (const float*)d_in[10];
  const float* inter= (const float*)d_in[11];
  const float* prot = (const float*)d_in[12];
  const float* mw   = (const float*)d_in[13];
  const float* mb   = (const float*)d_in[14];
  const float* w0 = (const float*)d_in[15]; const float* b0 = (const float*)d_in[16];
  const float* w1 = (const float*)d_in[17]; const float* b1 = (const float*)d_in[18];
  const float* w2 = (const float*)d_in[19]; const float* b2 = (const float*)d_in[20];
  const float* w3 = (const float*)d_in[21]; const float* b3 = (const float*)d_in[22];
  const float* w4 = (const float*)d_in[23]; const float* b4 = (const float*)d_in[24];

  // workspace: Xt 628 slabs | H1t 157 | H2t 40 | part (fp32)
  u16* Xt  = (u16*)d_ws;
  u16* H1t = Xt  + (size_t)628 * SLAB_U16;
  u16* H2t = H1t + (size_t)157 * SLAB_U16;
  float* part = (float*)(H2t + (size_t)40 * SLAB_U16);

  // split-K factor for L0 gated on workspace capacity (deterministic: ws_size
  // is fixed per harness). part needs S*512*5120*4 bytes after 27.0 MB of slabs.
  size_t base = (size_t)(628 + 157 + 40) * SLAB_U16 * 2;
  int S0 = 6;
  if (ws_size >= base + (size_t)12 * B_ * 5120 * 4) S0 = 12;
  else if (ws_size >= base + (size_t)8 * B_ * 5120 * 4) S0 = 8;

  // gene micro-MLP + clinical -> chunked X slabs (K = 20096 = 628*32)
  k_gene<<<dim3(80, 16), 256, 0, stream>>>(expr, bw1, bb1, bw2, bb2, gw, gb,
                                           cc, cnc, race, eth, inter, prot, mw, mb, Xt);

  // L0: (512 x 20038) @ (20038 x 5009), 628 slabs, BN=256 -> nt=20, split-K=S0
  k_gemm<<<dim3(20, S0), 1024, 0, stream>>>(Xt, w0, part, 628, 20038, 5009, 5120);
  k_reduce<<<2512, 256, 0, stream>>>(part, b0, H1t, S0, 5120, 5024, 5009);

  // L1: (512 x 5009) @ (5009 x 1252), 157 slabs, nt=5, split-K=24 -> 120 blocks
  k_gemm<<<dim3(5, 24), 1024, 0, stream>>>(H1t, w1, part, 157, 5009, 1252, 1280);
  k_reduce<<<640, 256, 0, stream>>>(part, b1, H2t, 24, 1280, 1280, 1252);

  // L2: (512 x 1252) @ (1252 x 313), 40 slabs, nt=2, split-K=20 -> 40 blocks
  k_gemm<<<dim3(2, 20), 1024, 0, stream>>>(H2t, w2, part, 40, 1252, 313, 512);

  // fused reduce(L2) + L3 + L4 tail
  k_tail<<<512, 128, 0, stream>>>(part, b2, w3, b3, w4, b4, 20, 512, (float*)d_out);
}